// Round 5
// baseline (710.668 us; speedup 1.0000x reference)
//
#include <hip/hip_runtime.h>
#include <stdint.h>

// Problem constants (N,C,H,W)=(4,96,96,96), half-res 48x48
#define BN_ 4
#define CC 96
#define HF 96
#define WF 96
#define HS 48
#define WS 48
#define LL 2304      // HS*WS
#define K1 864       // CC*9  (3x3 patch feature dim)
#define J2 1536      // CC*16 (4x4 raw filter feature dim)
#define NEG10 (-1.0e10f)

typedef __attribute__((ext_vector_type(8))) short short8v;
typedef __attribute__((ext_vector_type(8))) _Float16 half8v;
typedef __attribute__((ext_vector_type(4))) float float4v;

__device__ __forceinline__ int Tswap(int f) { return (f % 48) * 48 + f / 48; }

__device__ __forceinline__ unsigned short f2bf(float f) {
    union { float f; uint32_t u; } v; v.f = f;
    uint32_t u = v.u;
    uint32_t r = (u + 0x7fffu + ((u >> 16) & 1u)) >> 16;
    return (unsigned short)r;
}
__device__ __forceinline__ float bf2f(unsigned short h) {
    union { uint32_t u; float f; } v; v.u = ((uint32_t)h) << 16;
    return v.f;
}
__device__ __forceinline__ unsigned short f2h(float f) {
    _Float16 h = (_Float16)f;
    return __builtin_bit_cast(unsigned short, h);
}
__device__ __forceinline__ float h2f(unsigned short u) {
    return (float)__builtin_bit_cast(_Float16, u);
}

typedef const __attribute__((address_space(1))) uint32_t* gas_ptr;
typedef __attribute__((address_space(3))) uint32_t* las_ptr;
__device__ __forceinline__ void gload16(const void* g, void* l) {
    __builtin_amdgcn_global_load_lds((gas_ptr)g, (las_ptr)l, 16, 0, 0);
}

// ---- channel-sum-of-squares of strided context: ssum[n][i][j] ----
__global__ void ssum_kernel(const float* __restrict__ ctx, float* __restrict__ ssum) {
    int idx = blockIdx.x * 256 + threadIdx.x;
    if (idx >= BN_ * HS * WS) return;
    int j = idx % WS, i = (idx / WS) % HS, n = idx / (WS * HS);
    float s = 0.f;
    for (int c = 0; c < CC; ++c) {
        float v = ctx[((size_t)(n * CC + c) * HF + 2 * i) * WF + 2 * j];
        s += v * v;
    }
    ssum[idx] = s;
}

// ---- invn[n][l] = 1/max(sqrt(sum 3x3 ssum),1e-4) ----
__global__ void invn_kernel(const float* __restrict__ ssum, float* __restrict__ invn) {
    int idx = blockIdx.x * 256 + threadIdx.x;
    if (idx >= BN_ * LL) return;
    int l = idx % LL, n = idx / LL;
    int i0 = l / WS, j0 = l % WS;
    float s = 0.f;
    for (int dy = -1; dy <= 1; ++dy)
        for (int dx = -1; dx <= 1; ++dx) {
            int i = i0 + dy, j = j0 + dx;
            if (i >= 0 && i < HS && j >= 0 && j < WS)
                s += ssum[(n * HS + i) * WS + j];
        }
    invn[idx] = 1.f / fmaxf(sqrtf(s), 1e-4f);
}

// ---- maskadd[n][l] ----
__global__ void mask_kernel(const float* __restrict__ mask, float* __restrict__ maskadd) {
    int idx = blockIdx.x * 256 + threadIdx.x;
    if (idx >= BN_ * LL) return;
    int l = idx % LL, n = idx / LL;
    int i0 = l / WS, j0 = l % WS;
    float s = 0.f;
    for (int dy = -1; dy <= 1; ++dy)
        for (int dx = -1; dx <= 1; ++dx) {
            int i = i0 + dy, j = j0 + dx;
            if (i >= 0 && i < HS && j >= 0 && j < WS)
                s += mask[(size_t)n * HF * WF + (2 * i) * WF + 2 * j];
        }
    maskadd[idx] = (s > 0.f) ? NEG10 : 0.f;
}

// ---- im2col 3x3 (pad 1) of ::2 slice + bf16 hi/lo split; dst [n][l][864] k-major ----
__global__ void im2col_split(const float* __restrict__ src, const float* __restrict__ scale,
                             unsigned short* __restrict__ hi, unsigned short* __restrict__ lo) {
    int idx = blockIdx.x * 256 + threadIdx.x;
    if (idx >= BN_ * LL * K1) return;
    int k = idx % K1;
    int l = (idx / K1) % LL;
    int n = idx / (K1 * LL);
    int c = k / 9, r = k % 9;
    int i = l / WS + r / 3 - 1;
    int j = l % WS + r % 3 - 1;
    float v = 0.f;
    if (i >= 0 && i < HS && j >= 0 && j < WS)
        v = src[((size_t)(n * CC + c) * HF + 2 * i) * WF + 2 * j];
    if (scale) v *= scale[n * LL + l];
    unsigned short h = f2bf(v);
    hi[idx] = h;
    lo[idx] = f2bf(v - bf2f(h));
}

// ---- raw filter, transposed, f16: RF[n][j][l] ----
__global__ void rf_split(const float* __restrict__ ctx, unsigned short* __restrict__ hf) {
    int idx = blockIdx.x * 256 + threadIdx.x;
    if (idx >= BN_ * J2 * LL) return;
    int l = idx % LL;
    int j = (idx / LL) % J2;
    int n = idx / (LL * J2);
    int c = j >> 4, ky = (j >> 2) & 3, kx = j & 3;
    int y = 2 * (l / WS) + ky - 1;
    int x = 2 * (l % WS) + kx - 1;
    float v = 0.f;
    if (y >= 0 && y < HF && x >= 0 && x < WF)
        v = ctx[((size_t)(n * CC + c) * HF + y) * WF + x];
    hf[idx] = f2h(v);
}

// ---- MFMA GEMM: C[m][n] = sum_k A[m][k]*B[n][k] ----
// TERMS=3 (bf16): Ah*Bh + Ah*Bl + Al*Bh.  TERMS=1 (f16): Ah*Bh.
// ODT: 0 = fp32 out, 2 = f16 out. Flat 1D grid + XCD chunk swizzle (grid%8==0).
template <int TERMS, int ODT>
__global__ __launch_bounds__(256, 4) void gemm_split(
    const unsigned short* __restrict__ Ah_, const unsigned short* __restrict__ Al_,
    const unsigned short* __restrict__ Bh_, const unsigned short* __restrict__ Bl_,
    void* __restrict__ Cout, int M_, int N_, int K_, int nbx, int nby)
{
    constexpr int NB = (TERMS == 3) ? 4 : (TERMS == 2 ? 3 : 2);
    constexpr int BH = (TERMS >= 2) ? 2 : 1;       // B_hi LDS buffer index
    __shared__ unsigned short lds[NB][128][32];

    int wg = blockIdx.x;
    int wgid = (wg & 7) * (gridDim.x >> 3) + (wg >> 3);
    int bx = wgid % nbx;
    int t1 = wgid / nbx;
    int by = t1 % nby;
    int bz = t1 / nby;
    const int m0 = by * 128, n0 = bx * 128;
    const int t = threadIdx.x;

    const size_t sA = (size_t)M_ * K_, sB = (size_t)N_ * K_;
    const unsigned short* Ah = Ah_ + (size_t)bz * sA;
    const unsigned short* Bh = Bh_ + (size_t)bz * sB;

    const int rloc = t >> 2;
    const int sst = t & 3;
    const int kg = sst ^ ((rloc >> 1) & 3);
    const size_t offA0 = (size_t)(m0 + rloc) * K_ + kg * 8;
    const size_t offA1 = (size_t)(m0 + 64 + rloc) * K_ + kg * 8;
    const size_t offB0 = (size_t)(n0 + rloc) * K_ + kg * 8;
    const size_t offB1 = (size_t)(n0 + 64 + rloc) * K_ + kg * 8;
    const unsigned short* gpA0 = Ah + offA0;
    const unsigned short* gpA1 = Ah + offA1;
    const unsigned short* gpB0 = Bh + offB0;
    const unsigned short* gpB1 = Bh + offB1;
    const unsigned short* gpAl0 = nullptr;
    const unsigned short* gpAl1 = nullptr;
    const unsigned short* gpBl0 = nullptr;
    const unsigned short* gpBl1 = nullptr;
    if constexpr (TERMS >= 2) {
        const unsigned short* Al = Al_ + (size_t)bz * sA;
        gpAl0 = Al + offA0;
        gpAl1 = Al + offA1;
    }
    if constexpr (TERMS == 3) {
        const unsigned short* Bl = Bl_ + (size_t)bz * sB;
        gpBl0 = Bl + offB0;
        gpBl1 = Bl + offB1;
    }
    unsigned short* lpA0 = &lds[0][rloc][sst * 8];
    unsigned short* lpA1 = &lds[0][64 + rloc][sst * 8];
    unsigned short* lpB0 = &lds[BH][rloc][sst * 8];
    unsigned short* lpB1 = &lds[BH][64 + rloc][sst * 8];

    const int lane = t & 63;
    const int w = t >> 6, wr = w >> 1, wc = w & 1;
    const int lr = lane & 15, lg = lane >> 4;

    float4v acc[4][4] = {};

    for (int kt = 0; kt < K_; kt += 32) {
        __syncthreads();
        gload16(gpA0, lpA0); gload16(gpA1, lpA1);
        gload16(gpB0, lpB0); gload16(gpB1, lpB1);
        if constexpr (TERMS >= 2) {
            gload16(gpAl0, &lds[1][rloc][sst * 8]);
            gload16(gpAl1, &lds[1][64 + rloc][sst * 8]);
        }
        if constexpr (TERMS == 3) {
            gload16(gpBl0, &lds[3][rloc][sst * 8]);
            gload16(gpBl1, &lds[3][64 + rloc][sst * 8]);
        }
        gpA0 += 32; gpA1 += 32; gpB0 += 32; gpB1 += 32;
        if constexpr (TERMS >= 2) { gpAl0 += 32; gpAl1 += 32; }
        if constexpr (TERMS == 3) { gpBl0 += 32; gpBl1 += 32; }
        __syncthreads();

        if constexpr (TERMS == 1) {
            half8v bh[4];
#pragma unroll
            for (int j = 0; j < 4; ++j) {
                int row = wc * 64 + j * 16 + lr;
                int s = (lg ^ ((row >> 1) & 3)) * 8;
                bh[j] = *(const half8v*)&lds[BH][row][s];
            }
#pragma unroll
            for (int i = 0; i < 4; ++i) {
                int row = wr * 64 + i * 16 + lr;
                int s = (lg ^ ((row >> 1) & 3)) * 8;
                half8v ah = *(const half8v*)&lds[0][row][s];
#pragma unroll
                for (int j = 0; j < 4; ++j)
                    acc[i][j] = __builtin_amdgcn_mfma_f32_16x16x32_f16(ah, bh[j], acc[i][j], 0, 0, 0);
            }
        } else {
            short8v bh[4], bl[4];
#pragma unroll
            for (int j = 0; j < 4; ++j) {
                int row = wc * 64 + j * 16 + lr;
                int s = (lg ^ ((row >> 1) & 3)) * 8;
                bh[j] = *(const short8v*)&lds[BH][row][s];
                if constexpr (TERMS == 3) bl[j] = *(const short8v*)&lds[3][row][s];
            }
#pragma unroll
            for (int i = 0; i < 4; ++i) {
                int row = wr * 64 + i * 16 + lr;
                int s = (lg ^ ((row >> 1) & 3)) * 8;
                short8v ah = *(const short8v*)&lds[0][row][s];
                short8v al = *(const short8v*)&lds[1][row][s];
#pragma unroll
                for (int j = 0; j < 4; ++j) {
                    acc[i][j] = __builtin_amdgcn_mfma_f32_16x16x32_bf16(ah, bh[j], acc[i][j], 0, 0, 0);
                    if constexpr (TERMS == 3)
                        acc[i][j] = __builtin_amdgcn_mfma_f32_16x16x32_bf16(ah, bl[j], acc[i][j], 0, 0, 0);
                    acc[i][j] = __builtin_amdgcn_mfma_f32_16x16x32_bf16(al, bh[j], acc[i][j], 0, 0, 0);
                }
            }
        }
    }

    if constexpr (ODT == 0) {
        float* Cb = (float*)Cout + (size_t)bz * M_ * N_;
#pragma unroll
        for (int i = 0; i < 4; ++i) {
            int mb = m0 + wr * 64 + i * 16 + lg * 4;
#pragma unroll
            for (int j = 0; j < 4; ++j) {
                int nn = n0 + wc * 64 + j * 16 + lr;
#pragma unroll
                for (int r = 0; r < 4; ++r)
                    Cb[(size_t)(mb + r) * N_ + nn] = acc[i][j][r];
            }
        }
    } else {
        unsigned short* Gb = (unsigned short*)Cout + (size_t)bz * M_ * N_;
#pragma unroll
        for (int i = 0; i < 4; ++i) {
            int mb = m0 + wr * 64 + i * 16 + lg * 4;
#pragma unroll
            for (int j = 0; j < 4; ++j) {
                int nn = n0 + wc * 64 + j * 16 + lr;
#pragma unroll
                for (int r = 0; r < 4; ++r)
                    Gb[(size_t)(mb + r) * N_ + nn] = f2h(acc[i][j][r]);
            }
        }
    }
}

// ---- inline fused double conv_eye gather: F(l,p) = 10*sum9 S + maskadd[l] ----
// p-side stencil precomputed per thread (p fixed): p2v[d2], pok[d2].
__device__ __forceinline__ float fuse_gather(const float* __restrict__ Sb, int l,
                                             const int* p2v, const bool* pok,
                                             float madd) {
    int Tl = Tswap(l);
    float acc = 0.f;
#pragma unroll
    for (int d2 = 0; d2 < 3; ++d2) {
        int fl = Tl + d2 - 1;
        if (fl < 0 || fl >= LL || !pok[d2]) continue;
        int l2 = Tswap(fl);
        int pb = p2v[d2];
#pragma unroll
        for (int d1 = -1; d1 <= 1; ++d1) {
            int l3 = l2 + d1, p3 = pb + d1;
            if (l3 < 0 || l3 >= LL || p3 < 0 || p3 >= LL) continue;
            acc += Sb[(size_t)l3 * LL + p3];
        }
    }
    return acc * 10.f + madd;
}

// ---- colstat (fused gather): online (m,s) per column over an l-split ----
// grid (36 p-blocks, 8 l-splits, 4 n), block 256 = 64 p x 4 l-rows
__global__ __launch_bounds__(256) void colstat_fuse(const float* __restrict__ S,
                                                    const float* __restrict__ maskadd,
                                                    float* __restrict__ pm,
                                                    float* __restrict__ ps) {
    __shared__ float ms[4][64], ss[4][64];
    int pb = blockIdx.x, lsp = blockIdx.y, n = blockIdx.z;
    int tx = threadIdx.x & 63;
    int ty = threadIdx.x >> 6;
    int p = pb * 64 + tx;
    const float* Sb = S + (size_t)n * LL * LL;
    const float* mb = maskadd + n * LL;
    int Tp = Tswap(p);
    int p2v[3]; bool pok[3];
#pragma unroll
    for (int d2 = 0; d2 < 3; ++d2) {
        int fp = Tp + d2 - 1;
        pok[d2] = (fp >= 0 && fp < LL);
        p2v[d2] = pok[d2] ? Tswap(fp) : 0;
    }
    float m = -3e38f, s = 0.f;
    int l_end = (lsp + 1) * 288;
    for (int l = lsp * 288 + ty; l < l_end; l += 4) {
        float F = fuse_gather(Sb, l, p2v, pok, mb[l]);
        float mm = fmaxf(m, F);
        s = s * __expf(m - mm) + __expf(F - mm);
        m = mm;
    }
    ms[ty][tx] = m; ss[ty][tx] = s;
    __syncthreads();
    if (ty == 0) {
#pragma unroll
        for (int q = 1; q < 4; ++q) {
            float m2 = ms[q][tx], s2 = ss[q][tx];
            float mm = fmaxf(m, m2);
            s = s * __expf(m - mm) + s2 * __expf(m2 - mm);
            m = mm;
        }
        pm[((size_t)n * 8 + lsp) * LL + p] = m;
        ps[((size_t)n * 8 + lsp) * LL + p] = s;
    }
}

// ---- merge 8 partials -> mstat[p], sinv[p] ----
__global__ void mergestat_kernel(const float* __restrict__ pm, const float* __restrict__ ps,
                                 float* __restrict__ mstat, float* __restrict__ sinv) {
    int idx = blockIdx.x * 256 + threadIdx.x;
    if (idx >= BN_ * LL) return;
    int n = idx / LL, p = idx % LL;
    float m = -3e38f, s = 0.f;
#pragma unroll
    for (int q = 0; q < 8; ++q) {
        float m2 = pm[((size_t)n * 8 + q) * LL + p];
        float s2 = ps[((size_t)n * 8 + q) * LL + p];
        float mm = fmaxf(m, m2);
        s = s * __expf(m - mm) + s2 * __expf(m2 - mm);
        m = mm;
    }
    mstat[idx] = m;
    sinv[idx] = 1.f / s;
}

// ---- finish (fused gather): att = exp(F-m)*sinv -> d_out; emit f16 attT[p][l] ----
__global__ __launch_bounds__(256) void finish_fuse(const float* __restrict__ S,
                                                   const float* __restrict__ maskadd,
                                                   const float* __restrict__ mstat,
                                                   const float* __restrict__ sinv,
                                                   float* __restrict__ att,
                                                   unsigned short* __restrict__ Th) {
    __shared__ float tile[32][33];
    int n = blockIdx.z;
    int l0 = blockIdx.y * 32, p0 = blockIdx.x * 32;
    const float* Sb = S + (size_t)n * LL * LL;
    const float* mb = maskadd + n * LL;
    float* Ab = att + (size_t)n * LL * LL;
    int tx = threadIdx.x & 31, ty = threadIdx.x >> 5;
    int p = p0 + tx;
    float m = mstat[n * LL + p];
    float si = sinv[n * LL + p];
    int Tp = Tswap(p);
    int p2v[3]; bool pok[3];
#pragma unroll
    for (int d2 = 0; d2 < 3; ++d2) {
        int fp = Tp + d2 - 1;
        pok[d2] = (fp >= 0 && fp < LL);
        p2v[d2] = pok[d2] ? Tswap(fp) : 0;
    }
#pragma unroll
    for (int q = 0; q < 4; ++q) {
        int l = l0 + ty + q * 8;
        float F = fuse_gather(Sb, l, p2v, pok, mb[l]);
        float e = __expf(F - m) * si;
        Ab[(size_t)l * LL + p] = e;
        tile[ty + q * 8][tx] = e;
    }
    __syncthreads();
#pragma unroll
    for (int q = 0; q < 4; ++q) {
        int pp = p0 + ty + q * 8;
        float v = tile[tx][ty + q * 8];
        Th[((size_t)n * LL + pp) * LL + l0 + tx] = f2h(v);
    }
}

// ---- col2im gather from f16 G[p][j] + overlap division ----
__global__ void col2im_kernel(const unsigned short* __restrict__ G, float* __restrict__ out) {
    int idx = blockIdx.x * 256 + threadIdx.x;
    if (idx >= BN_ * CC * HF * WF) return;
    int x = idx % WF;
    int y = (idx / WF) % HF;
    int c = (idx / (WF * HF)) % CC;
    int n = idx / (WF * HF * CC);
    const unsigned short* Gb = G + (size_t)n * LL * J2;
    float acc = 0.f;
#pragma unroll
    for (int ky = 0; ky < 4; ++ky) {
        int ynum = y + 1 - ky;
        if (ynum & 1) continue;
        int iy = ynum >> 1;
        if (iy < 0 || iy >= HS) continue;
#pragma unroll
        for (int kx = 0; kx < 4; ++kx) {
            int xnum = x + 1 - kx;
            if (xnum & 1) continue;
            int ix = xnum >> 1;
            if (ix < 0 || ix >= WS) continue;
            acc += h2f(Gb[(size_t)(iy * WS + ix) * J2 + c * 16 + ky * 4 + kx]);
        }
    }
    float cy = (y == 0 || y == HF - 1) ? 1.f : 2.f;
    float cx = (x == 0 || x == WF - 1) ? 1.f : 2.f;
    out[idx] = acc / (cy * cx);
}

extern "C" void kernel_launch(void* const* d_in, const int* in_sizes, int n_in,
                              void* d_out, int out_size, void* d_ws, size_t ws_size,
                              hipStream_t stream) {
    const float* x       = (const float*)d_in[0];
    const float* context = (const float*)d_in[1];
    const float* mask    = (const float*)d_in[2];

    float* out = (float*)d_out;                                  // [4][96][96][96]
    float* att_region = out + (size_t)BN_ * CC * HF * WF;        // [4][2304][2304] fp32

    // workspace layout (bytes); proven ws_size >= 148,672,512 (rounds 3/4).
    //  phase A (through GEMM1): cols/xp @0..63,700,992 ; S @63,700,992..148,635,648
    //  phase B (colstat..finish; S LIVE): Th f16 @0..42,467,328 (dead cols/xp) ;
    //           stats @42,467,328..~43.1M ; maskadd @148,635,648
    //  phase C (after finish; S dead): RF f16 @63,700,992..92,012,544 ;
    //           G f16 @92,012,544..120,324,096
    char* wsb = (char*)d_ws;
    const size_t EK1 = (size_t)BN_ * LL * K1;      // 7,962,624
    const size_t ERF = (size_t)BN_ * J2 * LL;      // 14,155,776
    unsigned short* cols_hi = (unsigned short*)wsb;
    unsigned short* cols_lo = cols_hi + EK1;
    unsigned short* xp_hi   = cols_lo + EK1;
    unsigned short* xp_lo   = xp_hi + EK1;
    float* S = (float*)(wsb + 63700992);
    unsigned short* Th = (unsigned short*)wsb;                    // phase B
    float* pm    = (float*)(wsb + 42467328);                      // [4][8][2304]
    float* ps    = pm + (size_t)BN_ * 8 * LL;
    float* mstat = ps + (size_t)BN_ * 8 * LL;                     // [4][2304]
    float* sinv  = mstat + BN_ * LL;
    unsigned short* RF = (unsigned short*)(wsb + 63700992);       // phase C (S dead)
    unsigned short* G  = (unsigned short*)(wsb + 92012544);
    float* ssum    = (float*)(wsb + 63700992);                    // dead before S written
    float* invn    = ssum + BN_ * HS * WS;
    float* maskadd = (float*)(wsb + 148635648);

    ssum_kernel<<<(BN_ * HS * WS + 255) / 256, 256, 0, stream>>>(context, ssum);
    invn_kernel<<<(BN_ * LL + 255) / 256, 256, 0, stream>>>(ssum, invn);
    mask_kernel<<<(BN_ * LL + 255) / 256, 256, 0, stream>>>(mask, maskadd);

    im2col_split<<<(int)(EK1 / 256), 256, 0, stream>>>(x, nullptr, xp_hi, xp_lo);
    im2col_split<<<(int)(EK1 / 256), 256, 0, stream>>>(context, invn, cols_hi, cols_lo);

    // GEMM1 (3-term bf16 split): S[l][p] = cols . xp^T (fp32)
    gemm_split<3, 0><<<(LL / 128) * (LL / 128) * BN_, 256, 0, stream>>>(
        cols_hi, cols_lo, xp_hi, xp_lo, S, LL, LL, K1, LL / 128, LL / 128);

    // softmax over l with on-the-fly fuse (no F materialization)
    colstat_fuse<<<dim3(LL / 64, 8, BN_), 256, 0, stream>>>(S, maskadd, pm, ps);
    mergestat_kernel<<<(BN_ * LL + 255) / 256, 256, 0, stream>>>(pm, ps, mstat, sinv);
    finish_fuse<<<dim3(LL / 32, LL / 32, BN_), 256, 0, stream>>>(
        S, maskadd, mstat, sinv, att_region, Th);

    // raw filters f16 (S dead now)
    rf_split<<<(int)(ERF / 256), 256, 0, stream>>>(context, RF);

    // GEMM2 (1-term f16): G[p][j] = att^T . RF^T  (f16 out)
    gemm_split<1, 2><<<(J2 / 128) * (LL / 128) * BN_, 256, 0, stream>>>(
        Th, nullptr, RF, nullptr, G, LL, J2, LL, J2 / 128, LL / 128);

    // col2im gather + overlap normalization -> out
    col2im_kernel<<<(BN_ * CC * HF * WF + 255) / 256, 256, 0, stream>>>(G, out);
}

// Round 6
// 514.456 us; speedup vs baseline: 1.3814x; 1.3814x over previous
//
#include <hip/hip_runtime.h>
#include <stdint.h>

// Problem constants (N,C,H,W)=(4,96,96,96), half-res 48x48
#define BN_ 4
#define CC 96
#define HF 96
#define WF 96
#define HS 48
#define WS 48
#define LL 2304      // HS*WS
#define K1 864       // CC*9  (3x3 patch feature dim)
#define J2 1536      // CC*16 (4x4 raw filter feature dim)
#define NEG10 (-1.0e10f)

typedef __attribute__((ext_vector_type(8))) _Float16 half8v;
typedef __attribute__((ext_vector_type(4))) float float4v;

__device__ __forceinline__ int Tswap(int f) { return (f % 48) * 48 + f / 48; }

__device__ __forceinline__ unsigned short f2h(float f) {
    _Float16 h = (_Float16)f;
    return __builtin_bit_cast(unsigned short, h);
}
__device__ __forceinline__ float h2f(unsigned short u) {
    return (float)__builtin_bit_cast(_Float16, u);
}

typedef const __attribute__((address_space(1))) uint32_t* gas_ptr;
typedef __attribute__((address_space(3))) uint32_t* las_ptr;
__device__ __forceinline__ void gload16(const void* g, void* l) {
    __builtin_amdgcn_global_load_lds((gas_ptr)g, (las_ptr)l, 16, 0, 0);
}

// ---- channel-sum-of-squares of strided context: ssum[n][i][j] ----
__global__ void ssum_kernel(const float* __restrict__ ctx, float* __restrict__ ssum) {
    int idx = blockIdx.x * 256 + threadIdx.x;
    if (idx >= BN_ * HS * WS) return;
    int j = idx % WS, i = (idx / WS) % HS, n = idx / (WS * HS);
    float s = 0.f;
    for (int c = 0; c < CC; ++c) {
        float v = ctx[((size_t)(n * CC + c) * HF + 2 * i) * WF + 2 * j];
        s += v * v;
    }
    ssum[idx] = s;
}

// ---- invn[n][l] = 1/max(sqrt(sum 3x3 ssum),1e-4) ----
__global__ void invn_kernel(const float* __restrict__ ssum, float* __restrict__ invn) {
    int idx = blockIdx.x * 256 + threadIdx.x;
    if (idx >= BN_ * LL) return;
    int l = idx % LL, n = idx / LL;
    int i0 = l / WS, j0 = l % WS;
    float s = 0.f;
    for (int dy = -1; dy <= 1; ++dy)
        for (int dx = -1; dx <= 1; ++dx) {
            int i = i0 + dy, j = j0 + dx;
            if (i >= 0 && i < HS && j >= 0 && j < WS)
                s += ssum[(n * HS + i) * WS + j];
        }
    invn[idx] = 1.f / fmaxf(sqrtf(s), 1e-4f);
}

// ---- maskadd[n][l] ----
__global__ void mask_kernel(const float* __restrict__ mask, float* __restrict__ maskadd) {
    int idx = blockIdx.x * 256 + threadIdx.x;
    if (idx >= BN_ * LL) return;
    int l = idx % LL, n = idx / LL;
    int i0 = l / WS, j0 = l % WS;
    float s = 0.f;
    for (int dy = -1; dy <= 1; ++dy)
        for (int dx = -1; dx <= 1; ++dx) {
            int i = i0 + dy, j = j0 + dx;
            if (i >= 0 && i < HS && j >= 0 && j < WS)
                s += mask[(size_t)n * HF * WF + (2 * i) * WF + 2 * j];
        }
    maskadd[idx] = (s > 0.f) ? NEG10 : 0.f;
}

// ---- im2col 3x3 (pad 1) of ::2 slice + f16 hi/lo split; dst [n][l][864] k-major ----
__global__ void im2col_split(const float* __restrict__ src, const float* __restrict__ scale,
                             unsigned short* __restrict__ hi, unsigned short* __restrict__ lo) {
    int idx = blockIdx.x * 256 + threadIdx.x;
    if (idx >= BN_ * LL * K1) return;
    int k = idx % K1;
    int l = (idx / K1) % LL;
    int n = idx / (K1 * LL);
    int c = k / 9, r = k % 9;
    int i = l / WS + r / 3 - 1;
    int j = l % WS + r % 3 - 1;
    float v = 0.f;
    if (i >= 0 && i < HS && j >= 0 && j < WS)
        v = src[((size_t)(n * CC + c) * HF + 2 * i) * WF + 2 * j];
    if (scale) v *= scale[n * LL + l];
    unsigned short h = f2h(v);
    hi[idx] = h;
    lo[idx] = f2h(v - h2f(h));
}

// ---- raw filter, transposed, f16: RF[n][j][l] ----
__global__ void rf_split(const float* __restrict__ ctx, unsigned short* __restrict__ hf) {
    int idx = blockIdx.x * 256 + threadIdx.x;
    if (idx >= BN_ * J2 * LL) return;
    int l = idx % LL;
    int j = (idx / LL) % J2;
    int n = idx / (LL * J2);
    int c = j >> 4, ky = (j >> 2) & 3, kx = j & 3;
    int y = 2 * (l / WS) + ky - 1;
    int x = 2 * (l % WS) + kx - 1;
    float v = 0.f;
    if (y >= 0 && y < HF && x >= 0 && x < WF)
        v = ctx[((size_t)(n * CC + c) * HF + y) * WF + x];
    hf[idx] = f2h(v);
}

// ---- f16 MFMA GEMM: C[m][n] = sum_k A[m][k]*B[n][k] ----
// TERMS=3: Ah*Bh + Ah*Bl + Al*Bh (hi/lo f16 split).  TERMS=1: Ah*Bh.
// ODT: 0 = fp32 out, 1 = f16 out. Flat 1D grid + XCD chunk swizzle (grid%8==0).
template <int TERMS, int ODT>
__global__ __launch_bounds__(256, 4) void gemm_split(
    const unsigned short* __restrict__ Ah_, const unsigned short* __restrict__ Al_,
    const unsigned short* __restrict__ Bh_, const unsigned short* __restrict__ Bl_,
    void* __restrict__ Cout, int M_, int N_, int K_, int nbx, int nby)
{
    constexpr int NB = (TERMS == 3) ? 4 : 2;
    constexpr int BH = (TERMS == 3) ? 2 : 1;       // B_hi LDS buffer index
    __shared__ unsigned short lds[NB][128][32];

    int wg = blockIdx.x;
    int wgid = (wg & 7) * (gridDim.x >> 3) + (wg >> 3);
    int bx = wgid % nbx;
    int t1 = wgid / nbx;
    int by = t1 % nby;
    int bz = t1 / nby;
    const int m0 = by * 128, n0 = bx * 128;
    const int t = threadIdx.x;

    const size_t sA = (size_t)M_ * K_, sB = (size_t)N_ * K_;
    const unsigned short* Ah = Ah_ + (size_t)bz * sA;
    const unsigned short* Bh = Bh_ + (size_t)bz * sB;

    const int rloc = t >> 2;
    const int sst = t & 3;
    const int kg = sst ^ ((rloc >> 1) & 3);
    const size_t offA0 = (size_t)(m0 + rloc) * K_ + kg * 8;
    const size_t offA1 = (size_t)(m0 + 64 + rloc) * K_ + kg * 8;
    const size_t offB0 = (size_t)(n0 + rloc) * K_ + kg * 8;
    const size_t offB1 = (size_t)(n0 + 64 + rloc) * K_ + kg * 8;
    const unsigned short* gpA0 = Ah + offA0;
    const unsigned short* gpA1 = Ah + offA1;
    const unsigned short* gpB0 = Bh + offB0;
    const unsigned short* gpB1 = Bh + offB1;
    const unsigned short* gpAl0 = nullptr;
    const unsigned short* gpAl1 = nullptr;
    const unsigned short* gpBl0 = nullptr;
    const unsigned short* gpBl1 = nullptr;
    if constexpr (TERMS == 3) {
        const unsigned short* Al = Al_ + (size_t)bz * sA;
        const unsigned short* Bl = Bl_ + (size_t)bz * sB;
        gpAl0 = Al + offA0;
        gpAl1 = Al + offA1;
        gpBl0 = Bl + offB0;
        gpBl1 = Bl + offB1;
    }
    unsigned short* lpA0 = &lds[0][rloc][sst * 8];
    unsigned short* lpA1 = &lds[0][64 + rloc][sst * 8];
    unsigned short* lpB0 = &lds[BH][rloc][sst * 8];
    unsigned short* lpB1 = &lds[BH][64 + rloc][sst * 8];

    const int lane = t & 63;
    const int w = t >> 6, wr = w >> 1, wc = w & 1;
    const int lr = lane & 15, lg = lane >> 4;

    float4v acc[4][4] = {};

    for (int kt = 0; kt < K_; kt += 32) {
        __syncthreads();
        gload16(gpA0, lpA0); gload16(gpA1, lpA1);
        gload16(gpB0, lpB0); gload16(gpB1, lpB1);
        if constexpr (TERMS == 3) {
            gload16(gpAl0, &lds[1][rloc][sst * 8]);
            gload16(gpAl1, &lds[1][64 + rloc][sst * 8]);
            gload16(gpBl0, &lds[3][rloc][sst * 8]);
            gload16(gpBl1, &lds[3][64 + rloc][sst * 8]);
        }
        gpA0 += 32; gpA1 += 32; gpB0 += 32; gpB1 += 32;
        if constexpr (TERMS == 3) { gpAl0 += 32; gpAl1 += 32; gpBl0 += 32; gpBl1 += 32; }
        __syncthreads();

        half8v bh[4], bl[4];
#pragma unroll
        for (int j = 0; j < 4; ++j) {
            int row = wc * 64 + j * 16 + lr;
            int s = (lg ^ ((row >> 1) & 3)) * 8;
            bh[j] = *(const half8v*)&lds[BH][row][s];
            if constexpr (TERMS == 3) bl[j] = *(const half8v*)&lds[3][row][s];
        }
#pragma unroll
        for (int i = 0; i < 4; ++i) {
            int row = wr * 64 + i * 16 + lr;
            int s = (lg ^ ((row >> 1) & 3)) * 8;
            half8v ah = *(const half8v*)&lds[0][row][s];
#pragma unroll
            for (int j = 0; j < 4; ++j) {
                acc[i][j] = __builtin_amdgcn_mfma_f32_16x16x32_f16(ah, bh[j], acc[i][j], 0, 0, 0);
                if constexpr (TERMS == 3) {
                    half8v al = *(const half8v*)&lds[1][row][s];
                    acc[i][j] = __builtin_amdgcn_mfma_f32_16x16x32_f16(ah, bl[j], acc[i][j], 0, 0, 0);
                    acc[i][j] = __builtin_amdgcn_mfma_f32_16x16x32_f16(al, bh[j], acc[i][j], 0, 0, 0);
                }
            }
        }
    }

    if constexpr (ODT == 0) {
        float* Cb = (float*)Cout + (size_t)bz * M_ * N_;
#pragma unroll
        for (int i = 0; i < 4; ++i) {
            int mb = m0 + wr * 64 + i * 16 + lg * 4;
#pragma unroll
            for (int j = 0; j < 4; ++j) {
                int nn = n0 + wc * 64 + j * 16 + lr;
#pragma unroll
                for (int r = 0; r < 4; ++r)
                    Cb[(size_t)(mb + r) * N_ + nn] = acc[i][j][r];
            }
        }
    } else {
        unsigned short* Gb = (unsigned short*)Cout + (size_t)bz * M_ * N_;
#pragma unroll
        for (int i = 0; i < 4; ++i) {
            int mb = m0 + wr * 64 + i * 16 + lg * 4;
#pragma unroll
            for (int j = 0; j < 4; ++j) {
                int nn = n0 + wc * 64 + j * 16 + lr;
#pragma unroll
                for (int r = 0; r < 4; ++r)
                    Gb[(size_t)(mb + r) * N_ + nn] = f2h(acc[i][j][r]);
            }
        }
    }
}

// ---- fused double conv_eye + mask + x10, one thread per element: F[l][p] ----
__global__ void fuse_kernel(const float* __restrict__ S, const float* __restrict__ maskadd,
                            float* __restrict__ Sf) {
    int wg = blockIdx.x;
    int wgid = (wg & 7) * (gridDim.x >> 3) + (wg >> 3);
    int idx = wgid * 256 + threadIdx.x;
    int p = idx % LL;
    int l = (idx / LL) % LL;
    int n = idx / (LL * LL);
    const float* Sb = S + (size_t)n * LL * LL;
    int Tl = Tswap(l), Tp = Tswap(p);
    float acc = 0.f;
#pragma unroll
    for (int d2 = -1; d2 <= 1; ++d2) {
        int fl = Tl + d2, fp = Tp + d2;
        if (fl < 0 || fl >= LL || fp < 0 || fp >= LL) continue;
        int l2 = Tswap(fl), p2 = Tswap(fp);
#pragma unroll
        for (int d1 = -1; d1 <= 1; ++d1) {
            int l3 = l2 + d1, p3 = p2 + d1;
            if (l3 < 0 || l3 >= LL || p3 < 0 || p3 >= LL) continue;
            acc += Sb[(size_t)l3 * LL + p3];
        }
    }
    Sf[idx] = acc * 10.f + maskadd[n * LL + l];
}

// ---- column-wise online softmax stats over F[l][p]: partial (m,s) per l-split ----
// grid (36 p-blocks, 8 l-splits, 4 n), block 256 = 64 p x 4 l-rows
__global__ __launch_bounds__(256) void colstat_kernel(const float* __restrict__ F,
                                                      float* __restrict__ pm,
                                                      float* __restrict__ ps) {
    __shared__ float ms[4][64], ss[4][64];
    int pb = blockIdx.x, lsp = blockIdx.y, n = blockIdx.z;
    int tx = threadIdx.x & 63;
    int ty = threadIdx.x >> 6;
    int p = pb * 64 + tx;
    const float* Fb = F + (size_t)n * LL * LL;
    float m = -3e38f, s = 0.f;
    int l_end = (lsp + 1) * 288;
    for (int l = lsp * 288 + ty; l < l_end; l += 4) {
        float v = Fb[(size_t)l * LL + p];
        float mm = fmaxf(m, v);
        s = s * __expf(m - mm) + __expf(v - mm);
        m = mm;
    }
    ms[ty][tx] = m; ss[ty][tx] = s;
    __syncthreads();
    if (ty == 0) {
#pragma unroll
        for (int q = 1; q < 4; ++q) {
            float m2 = ms[q][tx], s2 = ss[q][tx];
            float mm = fmaxf(m, m2);
            s = s * __expf(m - mm) + s2 * __expf(m2 - mm);
            m = mm;
        }
        pm[((size_t)n * 8 + lsp) * LL + p] = m;
        ps[((size_t)n * 8 + lsp) * LL + p] = s;
    }
}

// ---- merge 8 partials -> mstat[p], sinv[p] ----
__global__ void mergestat_kernel(const float* __restrict__ pm, const float* __restrict__ ps,
                                 float* __restrict__ mstat, float* __restrict__ sinv) {
    int idx = blockIdx.x * 256 + threadIdx.x;
    if (idx >= BN_ * LL) return;
    int n = idx / LL, p = idx % LL;
    float m = -3e38f, s = 0.f;
#pragma unroll
    for (int q = 0; q < 8; ++q) {
        float m2 = pm[((size_t)n * 8 + q) * LL + p];
        float s2 = ps[((size_t)n * 8 + q) * LL + p];
        float mm = fmaxf(m, m2);
        s = s * __expf(m - mm) + s2 * __expf(m2 - mm);
        m = mm;
    }
    mstat[idx] = m;
    sinv[idx] = 1.f / s;
}

// ---- finish: att = exp(F-m)*sinv in place; emit transposed f16 attT[p][l] ----
__global__ __launch_bounds__(256) void finish_kernel(float* __restrict__ F,
                                                     const float* __restrict__ mstat,
                                                     const float* __restrict__ sinv,
                                                     unsigned short* __restrict__ Th) {
    __shared__ float tile[32][33];
    int n = blockIdx.z;
    int l0 = blockIdx.y * 32, p0 = blockIdx.x * 32;
    float* Fb = F + (size_t)n * LL * LL;
    int tx = threadIdx.x & 31, ty = threadIdx.x >> 5;
    float m = mstat[n * LL + p0 + tx];
    float si = sinv[n * LL + p0 + tx];
#pragma unroll
    for (int q = 0; q < 4; ++q) {
        int l = l0 + ty + q * 8;
        size_t o = (size_t)l * LL + p0 + tx;
        float e = __expf(Fb[o] - m) * si;
        Fb[o] = e;                 // in-place: F -> att (same element)
        tile[ty + q * 8][tx] = e;  // tile[li][pi]
    }
    __syncthreads();
#pragma unroll
    for (int q = 0; q < 4; ++q) {
        int p = p0 + ty + q * 8;
        float v = tile[tx][ty + q * 8];   // (p, l0+tx)
        Th[((size_t)n * LL + p) * LL + l0 + tx] = f2h(v);
    }
}

// ---- col2im gather from f16 G[p][j] + overlap division ----
__global__ void col2im_kernel(const unsigned short* __restrict__ G, float* __restrict__ out) {
    int idx = blockIdx.x * 256 + threadIdx.x;
    if (idx >= BN_ * CC * HF * WF) return;
    int x = idx % WF;
    int y = (idx / WF) % HF;
    int c = (idx / (WF * HF)) % CC;
    int n = idx / (WF * HF * CC);
    const unsigned short* Gb = G + (size_t)n * LL * J2;
    float acc = 0.f;
#pragma unroll
    for (int ky = 0; ky < 4; ++ky) {
        int ynum = y + 1 - ky;
        if (ynum & 1) continue;
        int iy = ynum >> 1;
        if (iy < 0 || iy >= HS) continue;
#pragma unroll
        for (int kx = 0; kx < 4; ++kx) {
            int xnum = x + 1 - kx;
            if (xnum & 1) continue;
            int ix = xnum >> 1;
            if (ix < 0 || ix >= WS) continue;
            acc += h2f(Gb[(size_t)(iy * WS + ix) * J2 + c * 16 + ky * 4 + kx]);
        }
    }
    float cy = (y == 0 || y == HF - 1) ? 1.f : 2.f;
    float cx = (x == 0 || x == WF - 1) ? 1.f : 2.f;
    out[idx] = acc / (cy * cx);
}

extern "C" void kernel_launch(void* const* d_in, const int* in_sizes, int n_in,
                              void* d_out, int out_size, void* d_ws, size_t ws_size,
                              hipStream_t stream) {
    const float* x       = (const float*)d_in[0];
    const float* context = (const float*)d_in[1];
    const float* mask    = (const float*)d_in[2];

    float* out = (float*)d_out;                                  // [4][96][96][96]
    float* att_region = out + (size_t)BN_ * CC * HF * WF;        // [4][2304][2304] fp32

    // workspace layout (bytes); proven ws_size >= 148,672,512 (rounds 3-5).
    //  phase A (through GEMM1): cols/xp f16-splits @0..63,700,992 ; S @63,700,992..148,635,648
    //  phase B (fuse..finish): F lives in d_out att region; Th f16 @0 (dead cols/xp) ;
    //           stats @141,557,760 (dead S tail after fuse)
    //  phase C (after finish; S dead): RF f16 @84,934,656 ; G f16 @113,246,208
    //  maskadd @148,635,648 ; ssum/invn @63,700,992 (dead before S written)
    char* wsb = (char*)d_ws;
    const size_t EK1 = (size_t)BN_ * LL * K1;      // 7,962,624
    const size_t ERF = (size_t)BN_ * J2 * LL;      // 14,155,776
    unsigned short* cols_hi = (unsigned short*)wsb;
    unsigned short* cols_lo = cols_hi + EK1;
    unsigned short* xp_hi   = cols_lo + EK1;
    unsigned short* xp_lo   = xp_hi + EK1;
    float* S = (float*)(wsb + 63700992);
    unsigned short* Th = (unsigned short*)wsb;                    // phase B
    unsigned short* RF = (unsigned short*)(wsb + 84934656);       // phase C (S dead)
    unsigned short* G  = (unsigned short*)(wsb + 113246208);
    float* pm    = (float*)(wsb + 141557760);                     // [4][8][2304]
    float* ps    = pm + (size_t)BN_ * 8 * LL;
    float* mstat = ps + (size_t)BN_ * 8 * LL;                     // [4][2304]
    float* sinv  = mstat + BN_ * LL;
    float* ssum    = (float*)(wsb + 63700992);                    // dead before S written
    float* invn    = ssum + BN_ * HS * WS;
    float* maskadd = (float*)(wsb + 148635648);

    ssum_kernel<<<(BN_ * HS * WS + 255) / 256, 256, 0, stream>>>(context, ssum);
    invn_kernel<<<(BN_ * LL + 255) / 256, 256, 0, stream>>>(ssum, invn);
    mask_kernel<<<(BN_ * LL + 255) / 256, 256, 0, stream>>>(mask, maskadd);

    im2col_split<<<(int)(EK1 / 256), 256, 0, stream>>>(x, nullptr, xp_hi, xp_lo);
    im2col_split<<<(int)(EK1 / 256), 256, 0, stream>>>(context, invn, cols_hi, cols_lo);

    // GEMM1 (3-term f16 split): S[l][p] = cols . xp^T (fp32)
    gemm_split<3, 0><<<(LL / 128) * (LL / 128) * BN_, 256, 0, stream>>>(
        cols_hi, cols_lo, xp_hi, xp_lo, S, LL, LL, K1, LL / 128, LL / 128);

    // fuse (both conv_eye passes) + mask + x10 -> att_region (d_out)
    fuse_kernel<<<(int)((size_t)BN_ * LL * LL / 256), 256, 0, stream>>>(S, maskadd, att_region);

    // softmax over l: coalesced column stats + in-place finish (emits f16 attT)
    colstat_kernel<<<dim3(LL / 64, 8, BN_), 256, 0, stream>>>(att_region, pm, ps);
    mergestat_kernel<<<(BN_ * LL + 255) / 256, 256, 0, stream>>>(pm, ps, mstat, sinv);
    finish_kernel<<<dim3(LL / 32, LL / 32, BN_), 256, 0, stream>>>(att_region, mstat, sinv, Th);

    // raw filters f16 (S dead now)
    rf_split<<<(int)(ERF / 256), 256, 0, stream>>>(context, RF);

    // GEMM2 (1-term f16): G[p][j] = att^T . RF^T  (f16 out)
    gemm_split<1, 1><<<(J2 / 128) * (LL / 128) * BN_, 256, 0, stream>>>(
        Th, nullptr, RF, nullptr, G, LL, J2, LL, J2 / 128, LL / 128);

    // col2im gather + overlap normalization -> out
    col2im_kernel<<<(BN_ * CC * HF * WF + 255) / 256, 256, 0, stream>>>(G, out);
}